// Round 6
// baseline (233.788 us; speedup 1.0000x reference)
//
#include <hip/hip_runtime.h>

// NetVladCNN: B=64, D=512, H=W=32 (N=1024), K=64
// K0 : pack w f32 -> bf16 padded LDS-image (16 d-blocks)[64 k][80 B] in ws
// K1 : feat = w @ x[b] per (b, 128n-tile). x staged via global_load_lds (async,
//      double-buffered); w frags from pre-padded bf16 image (conflict-free b128).
//      bf16 repack via v_cvt_pk_bf16_f32.
// K1b: softmax over H; vectorized dwordx4 loads + shfl-xor h-reduce; writes a
//      as bf16 padded image (b, n-block)[64 k][80 B]
// K2 : [THIS ROUND'S ONLY CHANGE] V = a @ x^T - 32*c; barrier-free + LDS-free:
//      a-frags direct from global (padded image, L2-warm), depth-3 reg ring;
//      x via depth-4 reg ring; fully unrolled (static ring indices);
//      fused L2-normalize over k. -> yw (B,K,D)
// K3 : transpose -> out (D,K,B)

typedef __attribute__((ext_vector_type(8))) short short8;
typedef __attribute__((ext_vector_type(4))) float f32x4;
typedef unsigned short u16;
typedef unsigned int u32;

union S8u { u32 q[4]; short8 s; };

__device__ __forceinline__ u32 pk2(float lo, float hi) {  // RNE bf16 pair pack
  union { float f; u32 u; } a, b; a.f = lo; b.f = hi;
  u32 xl = (a.u + 0x7fffu + ((a.u >> 16) & 1u)) >> 16;
  u32 xh = (b.u + 0x7fffu + ((b.u >> 16) & 1u)) & 0xffff0000u;
  return xl | xh;
}

__device__ __forceinline__ u32 cvtpk(float lo, float hi) {  // HW RNE bf16 pack
  u32 r;
  asm("v_cvt_pk_bf16_f32 %0, %1, %2" : "=v"(r) : "v"(lo), "v"(hi));
  return r;
}

typedef const __attribute__((address_space(1))) u32 GU32;
typedef __attribute__((address_space(3))) u32 LU32;
__device__ __forceinline__ void glds16(const void* g, void* l) {
  __builtin_amdgcn_global_load_lds((GU32*)g, (LU32*)l, 16, 0, 0);
}

// ---------------- K0: pack w into padded bf16 image ----------------
// wsw image: [i=d-block 16][k 64][40 u16] (32 data + 8 pad) = 80 KB
__global__ __launch_bounds__(256) void k0_packw(
    const float* __restrict__ w, u16* __restrict__ wsw)
{
  const int tg = blockIdx.x * 256 + threadIdx.x;   // 8192 threads
  const int dd4 = tg & 7, i = (tg >> 3) & 15, k = tg >> 7;
  f32x4 v = *(const f32x4*)(w + k * 512 + i * 32 + dd4 * 4);
  u32* dst = (u32*)(wsw + ((size_t)i * 64 + k) * 40 + dd4 * 4);
  dst[0] = pk2(v[0], v[1]);
  dst[1] = pk2(v[2], v[3]);
}

// ---------------- K1: features GEMM (glds double-buffer) ----------------
// grid 512 = (ntile 8)*(b 64); block 256 = 4 waves; block tile 64k x 128n, K=512.
__global__ __launch_bounds__(256, 2) void k1_features(
    const float* __restrict__ x, const u16* __restrict__ wsw,
    float* __restrict__ feat)
{
  const int blk = blockIdx.x;
  const int b = blk & 63, nt8 = blk >> 6;          // XCD = b%8
  const int nb = nt8 * 128;
  const int tid = threadIdx.x, lane = tid & 63, wv = tid >> 6;
  const int row = lane & 15, q = lane >> 4;

  __shared__ __align__(16) float xs[2][32][128];   // 32 KB
  __shared__ __align__(16) u16 wls[2][64][40];     // 10 KB

  const char* xbase = (const char*)(x + ((size_t)b << 19) + nb);
  const char* wbase = (const char*)wsw;
  const int dd0 = tid >> 5, cby = (tid & 31) * 16; // x glds decomposition

  f32x4 acc[4][2];
#pragma unroll
  for (int mt = 0; mt < 4; mt++)
#pragma unroll
    for (int nt = 0; nt < 2; nt++) acc[mt][nt] = (f32x4){0.f, 0.f, 0.f, 0.f};

#define STAGE1(d0, buf)                                                        \
  {                                                                            \
    char* lx = (char*)&xs[buf][0][0];                                          \
    _Pragma("unroll")                                                          \
    for (int j = 0; j < 4; j++) {                                              \
      const int dd = j * 8 + dd0;                                              \
      glds16(xbase + (size_t)((d0) + dd) * 4096 + cby,                         \
             lx + j * 4096 + tid * 16);                                        \
    }                                                                          \
    char* lw = (char*)&wls[buf][0][0];                                         \
    const char* gw = wbase + (size_t)((d0) >> 5) * 5120;                       \
    glds16(gw + tid * 16, lw + tid * 16);                                      \
    if (tid < 64) glds16(gw + 4096 + tid * 16, lw + 4096 + tid * 16);          \
  }

  STAGE1(0, 0);
  for (int i = 0; i < 16; i++) {
    const int buf = i & 1;
    __syncthreads();                        // drains glds for buf (vmcnt(0))
    if (i < 15) STAGE1((i + 1) * 32, buf ^ 1);

    short8 af[4];
#pragma unroll
    for (int mt = 0; mt < 4; mt++)
      af[mt] = *(const short8*)&wls[buf][mt * 16 + row][q * 8];
    short8 bfv[2];
#pragma unroll
    for (int nt = 0; nt < 2; nt++) {
      const int n = wv * 32 + nt * 16 + row;
      const int d8 = q * 8;
      float v0 = xs[buf][d8 + 0][n], v1 = xs[buf][d8 + 1][n];
      float v2 = xs[buf][d8 + 2][n], v3 = xs[buf][d8 + 3][n];
      float v4 = xs[buf][d8 + 4][n], v5 = xs[buf][d8 + 5][n];
      float v6 = xs[buf][d8 + 6][n], v7 = xs[buf][d8 + 7][n];
      S8u t;
      t.q[0] = cvtpk(v0, v1); t.q[1] = cvtpk(v2, v3);
      t.q[2] = cvtpk(v4, v5); t.q[3] = cvtpk(v6, v7);
      bfv[nt] = t.s;
    }
#pragma unroll
    for (int nt = 0; nt < 2; nt++)
#pragma unroll
      for (int mt = 0; mt < 4; mt++)
        acc[mt][nt] = __builtin_amdgcn_mfma_f32_16x16x32_bf16(af[mt], bfv[nt], acc[mt][nt], 0, 0, 0);
  }
#undef STAGE1

  float* fb = feat + ((size_t)b << 16);
  const int nbw = nb + wv * 32;
#pragma unroll
  for (int mt = 0; mt < 4; mt++)
#pragma unroll
    for (int nt = 0; nt < 2; nt++)
#pragma unroll
      for (int r = 0; r < 4; r++)   // C layout: col=lane&15, row=q*4+r
        fb[(mt * 16 + q * 4 + r) * 1024 + nbw + nt * 16 + row] = acc[mt][nt][r];
}

// ---------------- K1b: softmax over H -> padded a image (vectorized) -------
// apad image: [b][h=n-block 32][k 64][40 u16]
// per wave: one (b,k) row. lane = (hq = lane>>3) x (wl = (lane&7)*4 w-cols).
__global__ __launch_bounds__(256) void k1b_softmax(
    const float* __restrict__ feat, u16* __restrict__ apad)
{
  const int tid = threadIdx.x, wv = tid >> 6, lane = tid & 63;
  const int rid = blockIdx.x * 4 + wv;         // rid = b*64 + k
  const int b = rid >> 6, k = rid & 63;
  const float* f = feat + ((size_t)rid << 10);
  const int wl = (lane & 7) * 4;               // 4 w-columns per lane
  const int hq = lane >> 3;                    // h = hq + r*8

  f32x4 v[4];
#pragma unroll
  for (int r = 0; r < 4; r++)
    v[r] = *(const f32x4*)(f + (hq + r * 8) * 32 + wl);

  f32x4 m = v[0];
#pragma unroll
  for (int r = 1; r < 4; r++)
#pragma unroll
    for (int c = 0; c < 4; c++) m[c] = fmaxf(m[c], v[r][c]);
#pragma unroll
  for (int mk = 8; mk <= 32; mk <<= 1)
#pragma unroll
    for (int c = 0; c < 4; c++) m[c] = fmaxf(m[c], __shfl_xor(m[c], mk));

  f32x4 s = (f32x4){0.f, 0.f, 0.f, 0.f};
#pragma unroll
  for (int r = 0; r < 4; r++)
#pragma unroll
    for (int c = 0; c < 4; c++) { v[r][c] = __expf(v[r][c] - m[c]); s[c] += v[r][c]; }
#pragma unroll
  for (int mk = 8; mk <= 32; mk <<= 1)
#pragma unroll
    for (int c = 0; c < 4; c++) s[c] += __shfl_xor(s[c], mk);

  f32x4 inv;
#pragma unroll
  for (int c = 0; c < 4; c++) inv[c] = 1.0f / s[c];

#pragma unroll
  for (int r = 0; r < 4; r++) {
    const int h = hq + r * 8;
    u32* dst = (u32*)(apad + ((size_t)(b * 32 + h) * 64 + k) * 40 + wl);
    dst[0] = pk2(v[r][0] * inv[0], v[r][1] * inv[1]);
    dst[1] = pk2(v[r][2] * inv[2], v[r][3] * inv[3]);
  }
}

// ---------------- K2: aggregation + fused normalize (no LDS, no barriers) --
// grid 512 = (dt 8)*(b 64); block 256 = 4 waves; wave: 64k x 16d; 32 n-iters.
// a read direct from padded global image (stride 40 u16 per k, 16B aligned).
__global__ __launch_bounds__(256, 2) void k2_aggregate(
    const float* __restrict__ x, const u16* __restrict__ apad,
    const float* __restrict__ cc, float* __restrict__ yw)
{
  const int blk = blockIdx.x;
  const int b = blk & 63, dt = blk >> 6;       // XCD = b%8
  const int tid = threadIdx.x, lane = tid & 63, wv = tid >> 6;
  const int row = lane & 15, q = lane >> 4;

  const float* px0 = x + ((size_t)b << 19) + (size_t)(dt * 64 + wv * 16 + row) * 1024 + q * 8;
  // a-frag base for this lane: k-row = row (k = mt*16+row), elems q*8..q*8+8
  const u16* ab = apad + (size_t)b * 81920 + (size_t)row * 40 + q * 8;

  f32x4 acc[4];
#pragma unroll
  for (int mt = 0; mt < 4; mt++) acc[mt] = (f32x4){0.f, 0.f, 0.f, 0.f};

  f32x4 xp0[4], xp1[4];                        // x ring, depth 4 (HBM)
  short8 ap[3][4];                             // a ring, depth 3 slots (L2)
#pragma unroll
  for (int j = 0; j < 4; j++) {
    xp0[j] = *(const f32x4*)(px0 + j * 32);
    xp1[j] = *(const f32x4*)(px0 + j * 32 + 4);
  }
#pragma unroll
  for (int j = 0; j < 2; j++)
#pragma unroll
    for (int mt = 0; mt < 4; mt++)             // h-slab j: +j*2560 u16; k-tile: +mt*640
      ap[j][mt] = *(const short8*)(ab + (size_t)j * 2560 + mt * 640);

#pragma unroll
  for (int i = 0; i < 32; i++) {
    const f32x4 c0 = xp0[i & 3], c1 = xp1[i & 3];
    S8u t;
    t.q[0] = cvtpk(c0[0], c0[1]); t.q[1] = cvtpk(c0[2], c0[3]);
    t.q[2] = cvtpk(c1[0], c1[1]); t.q[3] = cvtpk(c1[2], c1[3]);
    const short8 bfv = t.s;
#pragma unroll
    for (int mt = 0; mt < 4; mt++)
      acc[mt] = __builtin_amdgcn_mfma_f32_16x16x32_bf16(ap[i % 3][mt], bfv, acc[mt], 0, 0, 0);
    if (i + 4 < 32) {
      xp0[i & 3] = *(const f32x4*)(px0 + (i + 4) * 32);
      xp1[i & 3] = *(const f32x4*)(px0 + (i + 4) * 32 + 4);
    }
    if (i + 2 < 32) {
#pragma unroll
      for (int mt = 0; mt < 4; mt++)
        ap[(i + 2) % 3][mt] = *(const short8*)(ab + (size_t)(i + 2) * 2560 + mt * 640);
    }
  }

  // epilogue: lane holds 16 k's for d = dcol; norm over k wave-local (quads)
  const int dcol = dt * 64 + wv * 16 + row;
  float v[16]; float ss = 0.f;
#pragma unroll
  for (int mt = 0; mt < 4; mt++)
#pragma unroll
    for (int r = 0; r < 4; r++) {
      const int k = mt * 16 + q * 4 + r;
      const float tv = acc[mt][r] - 32.0f * cc[k * 512 + dcol];  // Sum_n a = 32 exact
      v[mt * 4 + r] = tv; ss += tv * tv;
    }
  ss += __shfl_xor(ss, 16);
  ss += __shfl_xor(ss, 32);
  const float rn = 1.0f / fmaxf(sqrtf(ss), 1e-12f);  // 2nd normalize is identity
  float* yb = yw + ((size_t)b << 15) + dcol;
#pragma unroll
  for (int mt = 0; mt < 4; mt++)
#pragma unroll
    for (int r = 0; r < 4; r++)
      yb[(size_t)(mt * 16 + q * 4 + r) << 9] = v[mt * 4 + r] * rn;
}

// ---------------- K3: (B,K,D) -> (D,K,B) ----------------
__global__ __launch_bounds__(256) void k3_transpose(
    const float* __restrict__ yw, float* __restrict__ out)
{
  const int blk = blockIdx.x;
  const int k = blk & 63;
  const int dt = blk >> 6;
  const int d0 = dt * 64;
  const int tid = threadIdx.x;
  __shared__ float T[64][68];
  {
    const int bl = tid >> 2, seg = tid & 3;
    const float* src = yw + (size_t)bl * 32768 + k * 512 + d0 + seg * 16;
#pragma unroll
    for (int i = 0; i < 4; i++) {
      f32x4 v = *(const f32x4*)(src + i * 4);
#pragma unroll
      for (int jj = 0; jj < 4; jj++) T[seg * 16 + i * 4 + jj][bl] = v[jj];
    }
  }
  __syncthreads();
  {
    const int dl = tid >> 2, bseg = tid & 3;
    float* dst = out + (size_t)(d0 + dl) * 4096 + k * 64 + bseg * 16;
    const float* srcT = &T[dl][bseg * 16];
#pragma unroll
    for (int i = 0; i < 4; i++)
      *(f32x4*)(dst + i * 4) = *(const f32x4*)(srcT + i * 4);
  }
}

extern "C" void kernel_launch(void* const* d_in, const int* in_sizes, int n_in,
                              void* d_out, int out_size, void* d_ws, size_t ws_size,
                              hipStream_t stream) {
  const float* x = (const float*)d_in[0];
  const float* w = (const float*)d_in[1];
  const float* c = (const float*)d_in[2];
  float* out = (float*)d_out;
  char* ws = (char*)d_ws;
  float* feat = (float*)ws;                                  // 16 MiB f32 logits
  u16*   apad = (u16*)(ws + (size_t)16 * 1024 * 1024);       // 10 MiB padded a image
  float* yw   = (float*)(ws + (size_t)26 * 1024 * 1024);     //  8 MiB (B,K,D)
  u16*   wsw  = (u16*)(ws + (size_t)34 * 1024 * 1024);       // 80 KiB padded w image
  k0_packw    <<<dim3(32),   dim3(256), 0, stream>>>(w, wsw);
  k1_features <<<dim3(512),  dim3(256), 0, stream>>>(x, wsw, feat);
  k1b_softmax <<<dim3(1024), dim3(256), 0, stream>>>(feat, apad);
  k2_aggregate<<<dim3(512),  dim3(256), 0, stream>>>(x, apad, c, yw);
  k3_transpose<<<dim3(512),  dim3(256), 0, stream>>>(yw, out);
}

// Round 7
// 230.450 us; speedup vs baseline: 1.0145x; 1.0145x over previous
//
#include <hip/hip_runtime.h>

// NetVladCNN: B=64, D=512, H=W=32 (N=1024), K=64
// Best-measured configuration (R4/R5 ≈ 230.67 µs): reverts R6's K2 experiment.
// K0 : pack w f32 -> bf16 padded LDS-image (16 d-blocks)[64 k][80 B] in ws
// K1 : feat = w @ x[b] per (b, 128n-tile). x staged via global_load_lds (async,
//      double-buffered); w frags from pre-padded bf16 image (conflict-free b128).
//      bf16 repack via v_cvt_pk_bf16_f32.
// K1b: softmax over H; vectorized dwordx4 loads + shfl-xor h-reduce; writes a
//      as bf16 padded image (b, n-block)[64 k][80 B]
// K2 : V = a @ x^T - 32*c; a via glds contiguous image, x via pipelined reg
//      loads; grid 1024 x 128 thr (4 blocks/CU, 2-wave blocks); cvt_pk repack;
//      fused L2-normalize over k. -> yw (B,K,D)
// K3 : transpose -> out (D,K,B)

typedef __attribute__((ext_vector_type(8))) short short8;
typedef __attribute__((ext_vector_type(4))) float f32x4;
typedef unsigned short u16;
typedef unsigned int u32;

union S8u { u32 q[4]; short8 s; };

__device__ __forceinline__ u32 pk2(float lo, float hi) {  // RNE bf16 pair pack
  union { float f; u32 u; } a, b; a.f = lo; b.f = hi;
  u32 xl = (a.u + 0x7fffu + ((a.u >> 16) & 1u)) >> 16;
  u32 xh = (b.u + 0x7fffu + ((b.u >> 16) & 1u)) & 0xffff0000u;
  return xl | xh;
}

__device__ __forceinline__ u32 cvtpk(float lo, float hi) {  // HW RNE bf16 pack
  u32 r;
  asm("v_cvt_pk_bf16_f32 %0, %1, %2" : "=v"(r) : "v"(lo), "v"(hi));
  return r;
}

typedef const __attribute__((address_space(1))) u32 GU32;
typedef __attribute__((address_space(3))) u32 LU32;
__device__ __forceinline__ void glds16(const void* g, void* l) {
  __builtin_amdgcn_global_load_lds((GU32*)g, (LU32*)l, 16, 0, 0);
}

// ---------------- K0: pack w into padded bf16 image ----------------
// wsw image: [i=d-block 16][k 64][40 u16] (32 data + 8 pad) = 80 KB
__global__ __launch_bounds__(256) void k0_packw(
    const float* __restrict__ w, u16* __restrict__ wsw)
{
  const int tg = blockIdx.x * 256 + threadIdx.x;   // 8192 threads
  const int dd4 = tg & 7, i = (tg >> 3) & 15, k = tg >> 7;
  f32x4 v = *(const f32x4*)(w + k * 512 + i * 32 + dd4 * 4);
  u32* dst = (u32*)(wsw + ((size_t)i * 64 + k) * 40 + dd4 * 4);
  dst[0] = pk2(v[0], v[1]);
  dst[1] = pk2(v[2], v[3]);
}

// ---------------- K1: features GEMM (glds double-buffer) ----------------
// grid 512 = (ntile 8)*(b 64); block 256 = 4 waves; block tile 64k x 128n, K=512.
__global__ __launch_bounds__(256, 2) void k1_features(
    const float* __restrict__ x, const u16* __restrict__ wsw,
    float* __restrict__ feat)
{
  const int blk = blockIdx.x;
  const int b = blk & 63, nt8 = blk >> 6;          // XCD = b%8
  const int nb = nt8 * 128;
  const int tid = threadIdx.x, lane = tid & 63, wv = tid >> 6;
  const int row = lane & 15, q = lane >> 4;

  __shared__ __align__(16) float xs[2][32][128];   // 32 KB
  __shared__ __align__(16) u16 wls[2][64][40];     // 10 KB

  const char* xbase = (const char*)(x + ((size_t)b << 19) + nb);
  const char* wbase = (const char*)wsw;
  const int dd0 = tid >> 5, cby = (tid & 31) * 16; // x glds decomposition

  f32x4 acc[4][2];
#pragma unroll
  for (int mt = 0; mt < 4; mt++)
#pragma unroll
    for (int nt = 0; nt < 2; nt++) acc[mt][nt] = (f32x4){0.f, 0.f, 0.f, 0.f};

#define STAGE1(d0, buf)                                                        \
  {                                                                            \
    char* lx = (char*)&xs[buf][0][0];                                          \
    _Pragma("unroll")                                                          \
    for (int j = 0; j < 4; j++) {                                              \
      const int dd = j * 8 + dd0;                                              \
      glds16(xbase + (size_t)((d0) + dd) * 4096 + cby,                         \
             lx + j * 4096 + tid * 16);                                        \
    }                                                                          \
    char* lw = (char*)&wls[buf][0][0];                                         \
    const char* gw = wbase + (size_t)((d0) >> 5) * 5120;                       \
    glds16(gw + tid * 16, lw + tid * 16);                                      \
    if (tid < 64) glds16(gw + 4096 + tid * 16, lw + 4096 + tid * 16);          \
  }

  STAGE1(0, 0);
  for (int i = 0; i < 16; i++) {
    const int buf = i & 1;
    __syncthreads();                        // drains glds for buf (vmcnt(0))
    if (i < 15) STAGE1((i + 1) * 32, buf ^ 1);

    short8 af[4];
#pragma unroll
    for (int mt = 0; mt < 4; mt++)
      af[mt] = *(const short8*)&wls[buf][mt * 16 + row][q * 8];
    short8 bfv[2];
#pragma unroll
    for (int nt = 0; nt < 2; nt++) {
      const int n = wv * 32 + nt * 16 + row;
      const int d8 = q * 8;
      float v0 = xs[buf][d8 + 0][n], v1 = xs[buf][d8 + 1][n];
      float v2 = xs[buf][d8 + 2][n], v3 = xs[buf][d8 + 3][n];
      float v4 = xs[buf][d8 + 4][n], v5 = xs[buf][d8 + 5][n];
      float v6 = xs[buf][d8 + 6][n], v7 = xs[buf][d8 + 7][n];
      S8u t;
      t.q[0] = cvtpk(v0, v1); t.q[1] = cvtpk(v2, v3);
      t.q[2] = cvtpk(v4, v5); t.q[3] = cvtpk(v6, v7);
      bfv[nt] = t.s;
    }
#pragma unroll
    for (int nt = 0; nt < 2; nt++)
#pragma unroll
      for (int mt = 0; mt < 4; mt++)
        acc[mt][nt] = __builtin_amdgcn_mfma_f32_16x16x32_bf16(af[mt], bfv[nt], acc[mt][nt], 0, 0, 0);
  }
#undef STAGE1

  float* fb = feat + ((size_t)b << 16);
  const int nbw = nb + wv * 32;
#pragma unroll
  for (int mt = 0; mt < 4; mt++)
#pragma unroll
    for (int nt = 0; nt < 2; nt++)
#pragma unroll
      for (int r = 0; r < 4; r++)   // C layout: col=lane&15, row=q*4+r
        fb[(mt * 16 + q * 4 + r) * 1024 + nbw + nt * 16 + row] = acc[mt][nt][r];
}

// ---------------- K1b: softmax over H -> padded a image (vectorized) -------
// apad image: [b][h=n-block 32][k 64][40 u16]
// per wave: one (b,k) row. lane = (hq = lane>>3) x (wl = (lane&7)*4 w-cols).
__global__ __launch_bounds__(256) void k1b_softmax(
    const float* __restrict__ feat, u16* __restrict__ apad)
{
  const int tid = threadIdx.x, wv = tid >> 6, lane = tid & 63;
  const int rid = blockIdx.x * 4 + wv;         // rid = b*64 + k
  const int b = rid >> 6, k = rid & 63;
  const float* f = feat + ((size_t)rid << 10);
  const int wl = (lane & 7) * 4;               // 4 w-columns per lane
  const int hq = lane >> 3;                    // h = hq + r*8

  f32x4 v[4];
#pragma unroll
  for (int r = 0; r < 4; r++)
    v[r] = *(const f32x4*)(f + (hq + r * 8) * 32 + wl);

  f32x4 m = v[0];
#pragma unroll
  for (int r = 1; r < 4; r++)
#pragma unroll
    for (int c = 0; c < 4; c++) m[c] = fmaxf(m[c], v[r][c]);
#pragma unroll
  for (int mk = 8; mk <= 32; mk <<= 1)
#pragma unroll
    for (int c = 0; c < 4; c++) m[c] = fmaxf(m[c], __shfl_xor(m[c], mk));

  f32x4 s = (f32x4){0.f, 0.f, 0.f, 0.f};
#pragma unroll
  for (int r = 0; r < 4; r++)
#pragma unroll
    for (int c = 0; c < 4; c++) { v[r][c] = __expf(v[r][c] - m[c]); s[c] += v[r][c]; }
#pragma unroll
  for (int mk = 8; mk <= 32; mk <<= 1)
#pragma unroll
    for (int c = 0; c < 4; c++) s[c] += __shfl_xor(s[c], mk);

  f32x4 inv;
#pragma unroll
  for (int c = 0; c < 4; c++) inv[c] = 1.0f / s[c];

#pragma unroll
  for (int r = 0; r < 4; r++) {
    const int h = hq + r * 8;
    u32* dst = (u32*)(apad + ((size_t)(b * 32 + h) * 64 + k) * 40 + wl);
    dst[0] = pk2(v[r][0] * inv[0], v[r][1] * inv[1]);
    dst[1] = pk2(v[r][2] * inv[2], v[r][3] * inv[3]);
  }
}

// ---------------- K2: aggregation + fused normalize ----------------
// grid 1024 = (dt 16)*(b 64); block 128 = 2 waves; wave: 64k x 16d; 32 n-iters.
// 4 blocks/CU: 2-wave barriers, independent blocks absorb staging stalls.
__global__ __launch_bounds__(128, 2) void k2_aggregate(
    const float* __restrict__ x, const u16* __restrict__ apad,
    const float* __restrict__ cc, float* __restrict__ yw)
{
  const int blk = blockIdx.x;
  const int b = blk & 63, dt = blk >> 6;       // dt 0..15, XCD = b%8
  const int tid = threadIdx.x, lane = tid & 63, wv = tid >> 6;
  const int row = lane & 15, q = lane >> 4;

  __shared__ __align__(16) u16 als[2][64][40];   // 10 KB

  const char* abase = (const char*)(apad + (size_t)b * 32 * 64 * 40);
  const float* px0 = x + ((size_t)b << 19) + (size_t)(dt * 32 + wv * 16 + row) * 1024 + q * 8;

#define STAGEA(i, buf)                                                         \
  {                                                                            \
    char* la = (char*)&als[buf][0][0];                                         \
    const char* ga = abase + (size_t)(i) * 5120;                               \
    glds16(ga + tid * 16, la + tid * 16);                                      \
    glds16(ga + 2048 + tid * 16, la + 2048 + tid * 16);                        \
    if (tid < 64) glds16(ga + 4096 + tid * 16, la + 4096 + tid * 16);          \
  }

  f32x4 acc[4];
#pragma unroll
  for (int mt = 0; mt < 4; mt++) acc[mt] = (f32x4){0.f, 0.f, 0.f, 0.f};

  STAGEA(0, 0);
  f32x4 c0 = *(const f32x4*)px0;
  f32x4 c1 = *(const f32x4*)(px0 + 4);
  f32x4 p0, p1;
  for (int i = 0; i < 32; i++) {
    const int buf = i & 1;
    __syncthreads();                        // drains glds + reg loads from i-1
    if (i < 31) {
      STAGEA(i + 1, buf ^ 1);
      p0 = *(const f32x4*)(px0 + (i + 1) * 32);
      p1 = *(const f32x4*)(px0 + (i + 1) * 32 + 4);
    }
    S8u t;
    t.q[0] = cvtpk(c0[0], c0[1]); t.q[1] = cvtpk(c0[2], c0[3]);
    t.q[2] = cvtpk(c1[0], c1[1]); t.q[3] = cvtpk(c1[2], c1[3]);
    const short8 bfv = t.s;
#pragma unroll
    for (int mt = 0; mt < 4; mt++) {
      short8 af = *(const short8*)&als[buf][mt * 16 + row][q * 8];
      acc[mt] = __builtin_amdgcn_mfma_f32_16x16x32_bf16(af, bfv, acc[mt], 0, 0, 0);
    }
    c0 = p0; c1 = p1;
  }
#undef STAGEA

  // epilogue: lane holds 16 k's for d = dcol; norm over k wave-local (quads)
  const int dcol = dt * 32 + wv * 16 + row;
  float v[16]; float ss = 0.f;
#pragma unroll
  for (int mt = 0; mt < 4; mt++)
#pragma unroll
    for (int r = 0; r < 4; r++) {
      const int k = mt * 16 + q * 4 + r;
      const float tv = acc[mt][r] - 32.0f * cc[k * 512 + dcol];  // Sum_n a = 32 exact
      v[mt * 4 + r] = tv; ss += tv * tv;
    }
  ss += __shfl_xor(ss, 16);
  ss += __shfl_xor(ss, 32);
  const float rn = 1.0f / fmaxf(sqrtf(ss), 1e-12f);  // 2nd normalize is identity
  float* yb = yw + ((size_t)b << 15) + dcol;
#pragma unroll
  for (int mt = 0; mt < 4; mt++)
#pragma unroll
    for (int r = 0; r < 4; r++)
      yb[(size_t)(mt * 16 + q * 4 + r) << 9] = v[mt * 4 + r] * rn;
}

// ---------------- K3: (B,K,D) -> (D,K,B) ----------------
__global__ __launch_bounds__(256) void k3_transpose(
    const float* __restrict__ yw, float* __restrict__ out)
{
  const int blk = blockIdx.x;
  const int k = blk & 63;
  const int dt = blk >> 6;
  const int d0 = dt * 64;
  const int tid = threadIdx.x;
  __shared__ float T[64][68];
  {
    const int bl = tid >> 2, seg = tid & 3;
    const float* src = yw + (size_t)bl * 32768 + k * 512 + d0 + seg * 16;
#pragma unroll
    for (int i = 0; i < 4; i++) {
      f32x4 v = *(const f32x4*)(src + i * 4);
#pragma unroll
      for (int jj = 0; jj < 4; jj++) T[seg * 16 + i * 4 + jj][bl] = v[jj];
    }
  }
  __syncthreads();
  {
    const int dl = tid >> 2, bseg = tid & 3;
    float* dst = out + (size_t)(d0 + dl) * 4096 + k * 64 + bseg * 16;
    const float* srcT = &T[dl][bseg * 16];
#pragma unroll
    for (int i = 0; i < 4; i++)
      *(f32x4*)(dst + i * 4) = *(const f32x4*)(srcT + i * 4);
  }
}

extern "C" void kernel_launch(void* const* d_in, const int* in_sizes, int n_in,
                              void* d_out, int out_size, void* d_ws, size_t ws_size,
                              hipStream_t stream) {
  const float* x = (const float*)d_in[0];
  const float* w = (const float*)d_in[1];
  const float* c = (const float*)d_in[2];
  float* out = (float*)d_out;
  char* ws = (char*)d_ws;
  float* feat = (float*)ws;                                  // 16 MiB f32 logits
  u16*   apad = (u16*)(ws + (size_t)16 * 1024 * 1024);       // 10 MiB padded a image
  float* yw   = (float*)(ws + (size_t)26 * 1024 * 1024);     //  8 MiB (B,K,D)
  u16*   wsw  = (u16*)(ws + (size_t)34 * 1024 * 1024);       // 80 KiB padded w image
  k0_packw    <<<dim3(32),   dim3(256), 0, stream>>>(w, wsw);
  k1_features <<<dim3(512),  dim3(256), 0, stream>>>(x, wsw, feat);
  k1b_softmax <<<dim3(1024), dim3(256), 0, stream>>>(feat, apad);
  k2_aggregate<<<dim3(1024), dim3(128), 0, stream>>>(x, apad, c, yw);
  k3_transpose<<<dim3(512),  dim3(256), 0, stream>>>(yw, out);
}